// Round 12
// baseline (13142.754 us; speedup 1.0000x reference)
//
#include <hip/hip_runtime.h>
#include <hip/hip_fp16.h>
#include <math.h>

#define T_STEPS 128
#define B_SZ 256
#define AD 16
#define ZD 32
#define KM 8
#define HID 128
#define G4H 512
#define NTHR 512

// ws layout (4-byte word offsets)
// WS_WQ: 48*512*4 u32, packed f16 pairs, [d4][thread j][m]
//   d4  0..15 : W_hh0 row j; 16..31 : W_ih1 row j; 32..47 : W_hh1 row j
#define WS_WQ   0
#define WS_WI0  98304     // 8*512 u32 : W_ih0 row j packed pairs, [k][j]
#define WS_BS0  102400    // 512  b_ih0+b_hh0
#define WS_BS1  102912    // 512  b_ih1+b_hh1
#define WS_Q    103424    // 1024 Q = QL QL^T + 1e-3 I
#define WS_R    104448    // 256  R = RL RL^T + 1e-3 I

typedef float f32x4 __attribute__((ext_vector_type(4)));

__device__ __forceinline__ unsigned pk16(float lo, float hi) {
  unsigned a = __half_as_ushort(__float2half_rn(lo));
  unsigned b = __half_as_ushort(__float2half_rn(hi));
  return a | (b << 16);
}

__global__ void ssm_prep_kernel(const float* __restrict__ Wih0, const float* __restrict__ Whh0,
                                const float* __restrict__ Wih1, const float* __restrict__ Whh1,
                                const float* __restrict__ bih0, const float* __restrict__ bhh0,
                                const float* __restrict__ bih1, const float* __restrict__ bhh1,
                                const float* __restrict__ QL, const float* __restrict__ RL,
                                float* __restrict__ ws) {
  unsigned* wsu = (unsigned*)ws;
  int tid = blockIdx.x * blockDim.x + threadIdx.x;
  int nt = gridDim.x * blockDim.x;
  for (int j = tid; j < G4H; j += nt) {
    for (int d4 = 0; d4 < 48; ++d4) {
      for (int m = 0; m < 4; ++m) {
        int dd = (d4 & 15) * 4 + m;
        const float* src = (d4 < 16) ? Whh0 : (d4 < 32) ? Wih1 : Whh1;
        wsu[WS_WQ + (d4 * 512 + j) * 4 + m] =
            pk16(src[j * 128 + 2 * dd], src[j * 128 + 2 * dd + 1]);
      }
    }
    for (int k = 0; k < 8; ++k)
      wsu[WS_WI0 + k * 512 + j] = pk16(Wih0[j * 16 + 2 * k], Wih0[j * 16 + 2 * k + 1]);
    ws[WS_BS0 + j] = bih0[j] + bhh0[j];
    ws[WS_BS1 + j] = bih1[j] + bhh1[j];
  }
  for (int e = tid; e < ZD * ZD; e += nt) {
    int i = e >> 5, j = e & 31;
    float s = 0.f;
    for (int k = 0; k < ZD; ++k) s += QL[i * ZD + k] * QL[j * ZD + k];
    if (i == j) s += 0.001f;
    ws[WS_Q + e] = s;
  }
  for (int e = tid; e < AD * AD; e += nt) {
    int i = e >> 4, j = e & 15;
    float s = 0.f;
    for (int k = 0; k < AD; ++k) s += RL[i * AD + k] * RL[j * AD + k];
    if (i == j) s += 0.001f;
    ws[WS_R + e] = s;
  }
}

__device__ __forceinline__ float sigm(float x) { return 1.0f / (1.0f + expf(-x)); }
__device__ __forceinline__ float dotv(f32x4 a, f32x4 b) {
  return a[0] * b[0] + a[1] * b[1] + a[2] * b[2] + a[3] * b[3];
}
__device__ __forceinline__ void st_nt(float* p, float v) { __builtin_nontemporal_store(v, p); }
__device__ __forceinline__ void st_nt4(float* p, f32x4 v) {
  __builtin_nontemporal_store(v, (f32x4*)p);
}

__device__ __forceinline__ float dot2f(unsigned a, unsigned b, float c) {
#if __has_builtin(__builtin_amdgcn_fdot2)
  typedef _Float16 h2 __attribute__((ext_vector_type(2)));
  union U { unsigned u; h2 h; };
  U ua, ub; ua.u = a; ub.u = b;
  return __builtin_amdgcn_fdot2(ua.h, ub.h, c, false);
#else
  union U { unsigned u; _Float16 h[2]; };
  U ua, ub; ua.u = a; ub.u = b;
  return c + (float)ua.h[0] * (float)ub.h[0] + (float)ua.h[1] * (float)ub.h[1];
#endif
}

// ============================ Kernel 1: LSTM chain ============================
struct alignas(16) LS {
  unsigned ap[8];
  unsigned h0p[64];
  unsigned h1p[64];
  float g[G4H];
  float lgp[16];
};

__global__ void __launch_bounds__(NTHR, 2) ssm_lstm_kernel(
    const float* __restrict__ as_, const float* __restrict__ AK, const float* __restrict__ CK,
    const float* __restrict__ Wout, const float* __restrict__ bout,
    const float* __restrict__ ws, float* __restrict__ out) {
  __shared__ LS s;
  const int tid = threadIdx.x;
  const int b = blockIdx.x;
  const unsigned* wsu = (const unsigned*)ws;
  const uint4* Wg = (const uint4*)(wsu + WS_WQ);
  const f32x4* AK4 = (const f32x4*)AK;
  const f32x4* CK4 = (const f32x4*)CK;

  float* o_As = out + (size_t)T_STEPS * B_SZ * ZD + (size_t)T_STEPS * B_SZ * ZD * ZD +
                (size_t)T_STEPS * B_SZ * ZD + (size_t)T_STEPS * B_SZ * ZD * ZD;
  float* o_Cs = o_As + (size_t)(T_STEPS + 1) * B_SZ * ZD * ZD;
  float* o_a = o_Cs + (size_t)(T_STEPS + 1) * B_SZ * AD * ZD;

  const uint4* h0p4 = (const uint4*)s.h0p;
  const uint4* h1p4 = (const uint4*)s.h1p;
  const uint4* ap4 = (const uint4*)s.ap;

  unsigned wi0r[8];
  #pragma unroll
  for (int k = 0; k < 8; ++k) wi0r[k] = wsu[WS_WI0 + k * 512 + tid];
  const float bs0r = ws[WS_BS0 + tid];
  const float bs1r = ws[WS_BS1 + tid];
  float woutr[8];
  #pragma unroll
  for (int gi = 0; gi < KM; ++gi) woutr[gi] = (tid < HID) ? Wout[gi * HID + tid] : 0.f;
  float boutr[8];
  #pragma unroll
  for (int k = 0; k < KM; ++k) boutr[k] = bout[k];

  float c0r = 0.f, c1r = 0.f;

  if (tid < 64) { s.h0p[tid] = 0u; s.h1p[tid] = 0u; }
  if (tid < AD) {
    float v = as_[(size_t)b * AD + tid];
    ((__half*)s.ap)[tid] = __float2half_rn(v);
    st_nt(&o_a[(size_t)b * AD + tid], v);
  }
  if (tid < 256) {  // o_As[0] (w0 = ones)
    f32x4 acc = {0.f, 0.f, 0.f, 0.f};
    #pragma unroll
    for (int k = 0; k < KM; ++k) acc += AK4[k * 256 + tid];
    st_nt4(&o_As[(size_t)b * 1024 + tid * 4], acc);
  } else if (tid < 384) {  // o_Cs[0]
    int idx = tid - 256;
    f32x4 acc = {0.f, 0.f, 0.f, 0.f};
    #pragma unroll
    for (int k = 0; k < KM; ++k) acc += CK4[k * 128 + idx];
    st_nt4(&o_Cs[(size_t)b * 512 + idx * 4], acc);
  }
  __syncthreads();

  for (int t = 0; t < T_STEPS; ++t) {
    const size_t tb2 = (size_t)(t + 1) * B_SZ + b;

    // A: L0 gates (stream W_hh0)
    {
      float acc = bs0r;
      #pragma unroll
      for (int k4 = 0; k4 < 2; ++k4) {
        uint4 av = ap4[k4];
        acc = dot2f(av.x, wi0r[k4 * 4 + 0], acc);
        acc = dot2f(av.y, wi0r[k4 * 4 + 1], acc);
        acc = dot2f(av.z, wi0r[k4 * 4 + 2], acc);
        acc = dot2f(av.w, wi0r[k4 * 4 + 3], acc);
      }
      #pragma unroll
      for (int d4 = 0; d4 < 16; ++d4) {
        uint4 w = Wg[d4 * 512 + tid];
        uint4 hv = h0p4[d4];
        acc = dot2f(hv.x, w.x, acc);
        acc = dot2f(hv.y, w.y, acc);
        acc = dot2f(hv.z, w.z, acc);
        acc = dot2f(hv.w, w.w, acc);
      }
      s.g[tid] = acc;
    }
    __syncthreads();

    // B: h0/c0
    if (tid < HID) {
      float ig = sigm(s.g[tid]);
      float fg = sigm(s.g[HID + tid]);
      float gg = tanhf(s.g[2 * HID + tid]);
      float og = sigm(s.g[3 * HID + tid]);
      c0r = fg * c0r + ig * gg;
      ((__half*)s.h0p)[tid] = __float2half_rn(og * tanhf(c0r));
    }
    __syncthreads();

    // C: L1 gates (stream W_ih1 + W_hh1)
    {
      float acc = bs1r;
      #pragma unroll
      for (int d4 = 0; d4 < 16; ++d4) {
        uint4 w = Wg[(16 + d4) * 512 + tid];
        uint4 hv = h0p4[d4];
        acc = dot2f(hv.x, w.x, acc);
        acc = dot2f(hv.y, w.y, acc);
        acc = dot2f(hv.z, w.z, acc);
        acc = dot2f(hv.w, w.w, acc);
      }
      #pragma unroll
      for (int d4 = 0; d4 < 16; ++d4) {
        uint4 w = Wg[(32 + d4) * 512 + tid];
        uint4 hv = h1p4[d4];
        acc = dot2f(hv.x, w.x, acc);
        acc = dot2f(hv.y, w.y, acc);
        acc = dot2f(hv.z, w.z, acc);
        acc = dot2f(hv.w, w.w, acc);
      }
      s.g[tid] = acc;
    }
    __syncthreads();

    // D: h1/c1 + logit partials
    if (tid < HID) {
      float ig = sigm(s.g[tid]);
      float fg = sigm(s.g[HID + tid]);
      float gg = tanhf(s.g[2 * HID + tid]);
      float og = sigm(s.g[3 * HID + tid]);
      c1r = fg * c1r + ig * gg;
      float h1u = og * tanhf(c1r);
      ((__half*)s.h1p)[tid] = __float2half_rn(h1u);
      int w2 = tid >> 6, lane = tid & 63;
      #pragma unroll
      for (int gi = 0; gi < KM; ++gi) {
        float p = woutr[gi] * h1u;
        #pragma unroll
        for (int m = 32; m >= 1; m >>= 1) p += __shfl_xor(p, m);
        if (lane == 0) s.lgp[w2 * KM + gi] = p;
      }
    }
    __syncthreads();

    // E: softmax + einsum outputs + a prefetch
    {
      float lg[KM];
      float mx = -1e30f;
      #pragma unroll
      for (int k = 0; k < KM; ++k) {
        lg[k] = s.lgp[k] + s.lgp[KM + k] + boutr[k];
        mx = fmaxf(mx, lg[k]);
      }
      float sum = 0.f;
      #pragma unroll
      for (int k = 0; k < KM; ++k) { lg[k] = expf(lg[k] - mx); sum += lg[k]; }
      float inv = 1.0f / sum;
      #pragma unroll
      for (int k = 0; k < KM; ++k) lg[k] *= inv;
      if (tid < 256) {
        f32x4 acc = {0.f, 0.f, 0.f, 0.f};
        #pragma unroll
        for (int k = 0; k < KM; ++k) acc += lg[k] * AK4[k * 256 + tid];
        st_nt4(&o_As[tb2 * 1024 + tid * 4], acc);
      } else if (tid < 384) {
        int idx = tid - 256;
        f32x4 acc = {0.f, 0.f, 0.f, 0.f};
        #pragma unroll
        for (int k = 0; k < KM; ++k) acc += lg[k] * CK4[k * 128 + idx];
        st_nt4(&o_Cs[tb2 * 512 + idx * 4], acc);
      } else if (tid >= 448 && tid < 448 + AD && t < T_STEPS - 1) {
        int i = tid - 448;
        float v = as_[tb2 * AD + i];
        ((__half*)s.ap)[i] = __float2half_rn(v);
        st_nt(&o_a[tb2 * AD + i], v);
      }
    }
    __syncthreads();
  }
}

// ========== Kernel 2: Kalman chain (1 wave/batch, barrier-free, prefetched) ==========
struct alignas(16) KS {
  float P[ZD * 36];      // cov_p (symmetric)
  float An[ZD * 36];     // A_next
  float Mt[ZD * 36];     // cov_t rows; reused for M2
  float MtT[ZD * 36];    // transposes
  float Sy[ZD * 36];     // sym(cov_t)
  float ACt[ZD * 36];
  float Qs[ZD * 36];
  float C[AD * 36];
  float Aug[AD * 52];    // [S(16) | CP(32)] per row
  float Kk[ZD * 20];
  float Rs[AD * AD];
  float meanp[ZD], meant[ZD], r[AD], af[AD];
};

__global__ void __launch_bounds__(64, 1) ssm_kalman_kernel(
    const float* __restrict__ as_, const float* __restrict__ initm,
    const float* __restrict__ initc, const float* __restrict__ ws,
    float* __restrict__ out) {
  __shared__ KS s;
  const int l = threadIdx.x;
  const int b = blockIdx.x;
  const int rq = l >> 3, cq = l & 7;   // 4x4 tile coords for 32x32 outputs
  const int i16 = l >> 2, q4 = l & 3;  // 16-row phases

  float* o_means = out;
  float* o_covs = o_means + (size_t)T_STEPS * B_SZ * ZD;
  float* o_nmean = o_covs + (size_t)T_STEPS * B_SZ * ZD * ZD;
  float* o_ncovs = o_nmean + (size_t)T_STEPS * B_SZ * ZD;
  const float* o_As = o_ncovs + (size_t)T_STEPS * B_SZ * ZD * ZD;
  const float* o_Cs = o_As + (size_t)(T_STEPS + 1) * B_SZ * ZD * ZD;

  f32x4* P4 = (f32x4*)s.P;        // stride 9
  f32x4* An4 = (f32x4*)s.An;
  f32x4* Mt4 = (f32x4*)s.Mt;
  f32x4* MtT4 = (f32x4*)s.MtT;
  f32x4* Sy4 = (f32x4*)s.Sy;
  f32x4* ACt4 = (f32x4*)s.ACt;
  f32x4* Q4 = (f32x4*)s.Qs;
  f32x4* C4 = (f32x4*)s.C;
  f32x4* Aug4 = (f32x4*)s.Aug;    // stride 13; right half at +4
  f32x4* Kk4 = (f32x4*)s.Kk;      // stride 5
  f32x4* af4 = (f32x4*)s.af;
  const f32x4* r4 = (const f32x4*)s.r;
  const f32x4* meanp4 = (const f32x4*)s.meanp;
  const f32x4* meant4 = (const f32x4*)s.meant;

  // ---- init ----
  #pragma unroll
  for (int q = 0; q < 16; ++q) {
    int e = q * 64 + l;
    s.P[(e >> 5) * 36 + (e & 31)] = initc[e];
    s.Qs[(e >> 5) * 36 + (e & 31)] = ws[WS_Q + e];
  }
  #pragma unroll
  for (int q = 0; q < 4; ++q) s.Rs[q * 64 + l] = ws[WS_R + q * 64 + l];
  if (l < ZD) s.meanp[l] = initm[l];
  {
    const f32x4* gc = (const f32x4*)&o_Cs[(size_t)b * 512];
    C4[(l >> 3) * 9 + (l & 7)] = gc[l];
    { int idx = 64 + l; C4[(idx >> 3) * 9 + (idx & 7)] = gc[idx]; }
    const f32x4* ga = (const f32x4*)&o_As[((size_t)B_SZ + b) * 1024];
    #pragma unroll
    for (int q = 0; q < 4; ++q) { int idx = q * 64 + l; An4[(idx >> 3) * 9 + (idx & 7)] = ga[idx]; }
    if (l < 4) af4[l] = ((const f32x4*)&as_[(size_t)b * AD])[l];
  }
  __builtin_amdgcn_wave_barrier();

  for (int t = 0; t < T_STEPS; ++t) {
    const size_t tb = (size_t)t * B_SZ + b;

    // P0: issue prefetch for step t+1 (kept in registers until P9)
    f32x4 pfC0 = {0,0,0,0}, pfC1 = {0,0,0,0};
    f32x4 pfA0 = {0,0,0,0}, pfA1 = {0,0,0,0}, pfA2 = {0,0,0,0}, pfA3 = {0,0,0,0};
    f32x4 pfa = {0,0,0,0};
    const bool pf = (t < T_STEPS - 1);
    if (pf) {
      const f32x4* gc = (const f32x4*)&o_Cs[(tb + B_SZ) * 512];
      pfC0 = gc[l];
      pfC1 = gc[64 + l];
      const f32x4* ga = (const f32x4*)&o_As[(tb + 2 * B_SZ) * 1024];
      pfA0 = ga[l];
      pfA1 = ga[64 + l];
      pfA2 = ga[128 + l];
      pfA3 = ga[192 + l];
      if (l < 4) pfa = ((const f32x4*)&as_[(tb + B_SZ) * AD])[l];
    }

    // P1: CP = C @ P (P symmetric -> row dots) -> Aug right half (rows 2rq,2rq+1 x cols 4cq)
    {
      const int i0 = rq * 2, i1 = i0 + 1;
      float a0[4] = {0.f, 0.f, 0.f, 0.f}, a1[4] = {0.f, 0.f, 0.f, 0.f};
      #pragma unroll
      for (int k4 = 0; k4 < 8; ++k4) {
        f32x4 c0 = C4[i0 * 9 + k4], c1 = C4[i1 * 9 + k4];
        #pragma unroll
        for (int jjx = 0; jjx < 4; ++jjx) {
          int jj = (jjx + cq) & 3;  // bank stagger
          f32x4 pj = P4[(4 * cq + jj) * 9 + k4];
          a0[jj] += dotv(c0, pj);
          a1[jj] += dotv(c1, pj);
        }
      }
      f32x4 v0 = {a0[0], a0[1], a0[2], a0[3]};
      f32x4 v1 = {a1[0], a1[1], a1[2], a1[3]};
      Aug4[i0 * 13 + 4 + cq] = v0;
      Aug4[i1 * 13 + 4 + cq] = v1;
    }
    __builtin_amdgcn_wave_barrier();

    // P2: S = CP C^T + R -> Aug left (row i16, cols 4q4); r = a - C meanp (lanes<16)
    {
      float acc[4];
      #pragma unroll
      for (int jj = 0; jj < 4; ++jj) acc[jj] = s.Rs[i16 * AD + 4 * q4 + jj];
      #pragma unroll
      for (int k4 = 0; k4 < 8; ++k4) {
        f32x4 cpi = Aug4[i16 * 13 + 4 + k4];  // CP row i16, chunk k4
        #pragma unroll
        for (int jjx = 0; jjx < 4; ++jjx) {
          int jj = (jjx + q4) & 3;
          f32x4 cj = C4[(4 * q4 + jj) * 9 + k4];
          acc[jj] += dotv(cpi, cj);
        }
      }
      f32x4 v = {acc[0], acc[1], acc[2], acc[3]};
      Aug4[i16 * 13 + q4] = v;
      if (l < AD) {
        float rr = s.af[l];
        #pragma unroll
        for (int k4 = 0; k4 < 8; ++k4) rr -= dotv(C4[l * 9 + k4], meanp4[k4]);
        s.r[l] = rr;
      }
    }
    __builtin_amdgcn_wave_barrier();

    // P3: GJ on [S | CP] -> K rows (register columns, shfl)
    {
      const int lc = (l < 48) ? l : 47;
      float col[16];
      #pragma unroll
      for (int i = 0; i < AD; ++i) col[i] = s.Aug[i * 52 + lc];
      #pragma unroll
      for (int j = 0; j < AD; ++j) {
        float pd = __shfl(col[j], j);
        float pinv = 1.0f / pd;
        float oldj = col[j];
        #pragma unroll
        for (int i = 0; i < AD; ++i) {
          if (i == j) continue;
          float fi = __shfl(col[i], j);
          col[i] = fmaf(-(fi * pinv), oldj, col[i]);
        }
        col[j] = oldj * pinv;
      }
      if (l >= AD && l < AD + ZD) {
        int rr = l - AD;
        f32x4 v0 = {col[0], col[1], col[2], col[3]};
        f32x4 v1 = {col[4], col[5], col[6], col[7]};
        f32x4 v2 = {col[8], col[9], col[10], col[11]};
        f32x4 v3 = {col[12], col[13], col[14], col[15]};
        Kk4[rr * 5 + 0] = v0;
        Kk4[rr * 5 + 1] = v1;
        Kk4[rr * 5 + 2] = v2;
        Kk4[rr * 5 + 3] = v3;
      }
    }
    __builtin_amdgcn_wave_barrier();

    // P4: mean_t (lanes<32) + cov_t = P - K@CP -> Mt, MtT (4x4 tile, k4-outer)
    {
      if (l < ZD) {
        float acc = s.meanp[l];
        #pragma unroll
        for (int m = 0; m < 4; ++m) acc += dotv(Kk4[l * 5 + m], r4[m]);
        s.meant[l] = acc;
        st_nt(&o_means[tb * ZD + l], acc);
      }
      f32x4 av0 = {0,0,0,0}, av1 = {0,0,0,0}, av2 = {0,0,0,0}, av3 = {0,0,0,0};
      #pragma unroll
      for (int k4 = 0; k4 < 4; ++k4) {
        f32x4 kch[4];
        #pragma unroll
        for (int iix = 0; iix < 4; ++iix) {
          int ii = (iix + rq) & 3;
          kch[ii] = Kk4[(4 * rq + ii) * 5 + k4];
        }
        #pragma unroll
        for (int kk = 0; kk < 4; ++kk) {
          f32x4 cpk = Aug4[(4 * k4 + kk) * 13 + 4 + cq];  // CP row k, cols 4cq..
          av0 += kch[0][kk] * cpk;
          av1 += kch[1][kk] * cpk;
          av2 += kch[2][kk] * cpk;
          av3 += kch[3][kk] * cpk;
        }
      }
      f32x4 m0 = P4[(4 * rq + 0) * 9 + cq] - av0;
      f32x4 m1 = P4[(4 * rq + 1) * 9 + cq] - av1;
      f32x4 m2 = P4[(4 * rq + 2) * 9 + cq] - av2;
      f32x4 m3 = P4[(4 * rq + 3) * 9 + cq] - av3;
      Mt4[(4 * rq + 0) * 9 + cq] = m0;
      Mt4[(4 * rq + 1) * 9 + cq] = m1;
      Mt4[(4 * rq + 2) * 9 + cq] = m2;
      Mt4[(4 * rq + 3) * 9 + cq] = m3;
      #pragma unroll
      for (int jj = 0; jj < 4; ++jj) {
        f32x4 tv = {m0[jj], m1[jj], m2[jj], m3[jj]};
        MtT4[(4 * cq + jj) * 9 + rq] = tv;
      }
    }
    __builtin_amdgcn_wave_barrier();

    // P5: Sy = 0.5(Mt+MtT) -> Sy + covs out
    {
      int i = l >> 1, cb = (l & 1) * 4;
      #pragma unroll
      for (int c = 0; c < 4; ++c) {
        f32x4 sv = 0.5f * (Mt4[i * 9 + cb + c] + MtT4[i * 9 + cb + c]);
        Sy4[i * 9 + cb + c] = sv;
        st_nt4(&o_covs[tb * 1024 + i * 32 + (cb + c) * 4], sv);
      }
    }
    __builtin_amdgcn_wave_barrier();

    // P6: ACt = An @ Sy (Sy symmetric -> row dots; 4x4 tile, k4-outer)
    {
      float acc[4][4] = {{0.f,0.f,0.f,0.f},{0.f,0.f,0.f,0.f},{0.f,0.f,0.f,0.f},{0.f,0.f,0.f,0.f}};
      #pragma unroll
      for (int k4 = 0; k4 < 8; ++k4) {
        f32x4 an[4], sy[4];
        #pragma unroll
        for (int iix = 0; iix < 4; ++iix) {
          int ii = (iix + rq) & 3;
          an[ii] = An4[(4 * rq + ii) * 9 + k4];
        }
        #pragma unroll
        for (int jjx = 0; jjx < 4; ++jjx) {
          int jj = (jjx + cq) & 3;
          sy[jj] = Sy4[(4 * cq + jj) * 9 + k4];
        }
        #pragma unroll
        for (int ii = 0; ii < 4; ++ii) {
          #pragma unroll
          for (int jj = 0; jj < 4; ++jj) acc[ii][jj] += dotv(an[ii], sy[jj]);
        }
      }
      #pragma unroll
      for (int ii = 0; ii < 4; ++ii) {
        f32x4 v = {acc[ii][0], acc[ii][1], acc[ii][2], acc[ii][3]};
        ACt4[(4 * rq + ii) * 9 + cq] = v;
      }
    }
    __builtin_amdgcn_wave_barrier();

    // P7: M2 = ACt @ An^T -> Mt/MtT (reuse) + meanp' = An @ mean_t (lanes<32)
    {
      if (l < ZD) {
        float acc = 0.f;
        #pragma unroll
        for (int k4 = 0; k4 < 8; ++k4) acc += dotv(An4[l * 9 + k4], meant4[k4]);
        s.meanp[l] = acc;
        st_nt(&o_nmean[tb * ZD + l], acc);
      }
      float acc[4][4] = {{0.f,0.f,0.f,0.f},{0.f,0.f,0.f,0.f},{0.f,0.f,0.f,0.f},{0.f,0.f,0.f,0.f}};
      #pragma unroll
      for (int k4 = 0; k4 < 8; ++k4) {
        f32x4 ac[4], an[4];
        #pragma unroll
        for (int iix = 0; iix < 4; ++iix) {
          int ii = (iix + rq) & 3;
          ac[ii] = ACt4[(4 * rq + ii) * 9 + k4];
        }
        #pragma unroll
        for (int jjx = 0; jjx < 4; ++jjx) {
          int jj = (jjx + cq) & 3;
          an[jj] = An4[(4 * cq + jj) * 9 + k4];
        }
        #pragma unroll
        for (int ii = 0; ii < 4; ++ii) {
          #pragma unroll
          for (int jj = 0; jj < 4; ++jj) acc[ii][jj] += dotv(ac[ii], an[jj]);
        }
      }
      f32x4 m0 = {acc[0][0], acc[0][1], acc[0][2], acc[0][3]};
      f32x4 m1 = {acc[1][0], acc[1][1], acc[1][2], acc[1][3]};
      f32x4 m2 = {acc[2][0], acc[2][1], acc[2][2], acc[2][3]};
      f32x4 m3 = {acc[3][0], acc[3][1], acc[3][2], acc[3][3]};
      Mt4[(4 * rq + 0) * 9 + cq] = m0;
      Mt4[(4 * rq + 1) * 9 + cq] = m1;
      Mt4[(4 * rq + 2) * 9 + cq] = m2;
      Mt4[(4 * rq + 3) * 9 + cq] = m3;
      #pragma unroll
      for (int jj = 0; jj < 4; ++jj) {
        f32x4 tv = {m0[jj], m1[jj], m2[jj], m3[jj]};
        MtT4[(4 * cq + jj) * 9 + rq] = tv;
      }
    }
    __builtin_amdgcn_wave_barrier();

    // P8: P' = 0.5(M2+M2^T) + Q -> P + ncovs out
    {
      int i = l >> 1, cb = (l & 1) * 4;
      #pragma unroll
      for (int c = 0; c < 4; ++c) {
        f32x4 pv = 0.5f * (Mt4[i * 9 + cb + c] + MtT4[i * 9 + cb + c]) + Q4[i * 9 + cb + c];
        P4[i * 9 + cb + c] = pv;
        st_nt4(&o_ncovs[tb * 1024 + i * 32 + (cb + c) * 4], pv);
      }
    }
    __builtin_amdgcn_wave_barrier();

    // P9: commit prefetch to LDS for step t+1
    if (pf) {
      C4[(l >> 3) * 9 + (l & 7)] = pfC0;
      { int idx = 64 + l; C4[(idx >> 3) * 9 + (idx & 7)] = pfC1; }
      An4[(l >> 3) * 9 + (l & 7)] = pfA0;
      { int idx = 64 + l;  An4[(idx >> 3) * 9 + (idx & 7)] = pfA1; }
      { int idx = 128 + l; An4[(idx >> 3) * 9 + (idx & 7)] = pfA2; }
      { int idx = 192 + l; An4[(idx >> 3) * 9 + (idx & 7)] = pfA3; }
      if (l < 4) af4[l] = pfa;
    }
    __builtin_amdgcn_wave_barrier();
  }
}

extern "C" void kernel_launch(void* const* d_in, const int* in_sizes, int n_in,
                              void* d_out, int out_size, void* d_ws, size_t ws_size,
                              hipStream_t stream) {
  const float* as_ = (const float*)d_in[0];
  const float* AK = (const float*)d_in[1];
  const float* CK = (const float*)d_in[2];
  const float* QL = (const float*)d_in[3];
  const float* RL = (const float*)d_in[4];
  const float* initm = (const float*)d_in[5];
  const float* initc = (const float*)d_in[6];
  const float* Wih0 = (const float*)d_in[7];
  const float* Whh0 = (const float*)d_in[8];
  const float* bih0 = (const float*)d_in[9];
  const float* bhh0 = (const float*)d_in[10];
  const float* Wih1 = (const float*)d_in[11];
  const float* Whh1 = (const float*)d_in[12];
  const float* bih1 = (const float*)d_in[13];
  const float* bhh1 = (const float*)d_in[14];
  const float* Wout = (const float*)d_in[15];
  const float* bout = (const float*)d_in[16];
  float* ws = (float*)d_ws;
  float* out = (float*)d_out;

  ssm_prep_kernel<<<16, 256, 0, stream>>>(Wih0, Whh0, Wih1, Whh1, bih0, bhh0, bih1, bhh1,
                                          QL, RL, ws);
  ssm_lstm_kernel<<<B_SZ, NTHR, 0, stream>>>(as_, AK, CK, Wout, bout, ws, out);
  ssm_kalman_kernel<<<B_SZ, 64, 0, stream>>>(as_, initm, initc, ws, out);
}

// Round 13
// 1894.475 us; speedup vs baseline: 6.9374x; 6.9374x over previous
//
#include <hip/hip_runtime.h>
#include <hip/hip_fp16.h>
#include <math.h>

#define T_STEPS 128
#define B_SZ 256
#define AD 16
#define ZD 32
#define KM 8
#define HID 128
#define G4H 512
#define NTHR 512

// ws layout (4-byte word offsets)
// WS_WQ: 48*512*4 u32, packed f16 pairs, [d4][thread j][m]
//   d4  0..15 : W_hh0 row j; 16..31 : W_ih1 row j; 32..47 : W_hh1 row j
#define WS_WQ   0
#define WS_WI0  98304     // 8*512 u32 : W_ih0 row j packed pairs, [k][j]
#define WS_BS0  102400    // 512  b_ih0+b_hh0
#define WS_BS1  102912    // 512  b_ih1+b_hh1
#define WS_Q    103424    // 1024 Q = QL QL^T + 1e-3 I
#define WS_R    104448    // 256  R = RL RL^T + 1e-3 I

typedef float f32x4 __attribute__((ext_vector_type(4)));

__device__ __forceinline__ unsigned pk16(float lo, float hi) {
  unsigned a = __half_as_ushort(__float2half_rn(lo));
  unsigned b = __half_as_ushort(__float2half_rn(hi));
  return a | (b << 16);
}

__global__ void ssm_prep_kernel(const float* __restrict__ Wih0, const float* __restrict__ Whh0,
                                const float* __restrict__ Wih1, const float* __restrict__ Whh1,
                                const float* __restrict__ bih0, const float* __restrict__ bhh0,
                                const float* __restrict__ bih1, const float* __restrict__ bhh1,
                                const float* __restrict__ QL, const float* __restrict__ RL,
                                float* __restrict__ ws) {
  unsigned* wsu = (unsigned*)ws;
  int tid = blockIdx.x * blockDim.x + threadIdx.x;
  int nt = gridDim.x * blockDim.x;
  for (int j = tid; j < G4H; j += nt) {
    for (int d4 = 0; d4 < 48; ++d4) {
      for (int m = 0; m < 4; ++m) {
        int dd = (d4 & 15) * 4 + m;
        const float* src = (d4 < 16) ? Whh0 : (d4 < 32) ? Wih1 : Whh1;
        wsu[WS_WQ + (d4 * 512 + j) * 4 + m] =
            pk16(src[j * 128 + 2 * dd], src[j * 128 + 2 * dd + 1]);
      }
    }
    for (int k = 0; k < 8; ++k)
      wsu[WS_WI0 + k * 512 + j] = pk16(Wih0[j * 16 + 2 * k], Wih0[j * 16 + 2 * k + 1]);
    ws[WS_BS0 + j] = bih0[j] + bhh0[j];
    ws[WS_BS1 + j] = bih1[j] + bhh1[j];
  }
  for (int e = tid; e < ZD * ZD; e += nt) {
    int i = e >> 5, j = e & 31;
    float s = 0.f;
    for (int k = 0; k < ZD; ++k) s += QL[i * ZD + k] * QL[j * ZD + k];
    if (i == j) s += 0.001f;
    ws[WS_Q + e] = s;
  }
  for (int e = tid; e < AD * AD; e += nt) {
    int i = e >> 4, j = e & 15;
    float s = 0.f;
    for (int k = 0; k < AD; ++k) s += RL[i * AD + k] * RL[j * AD + k];
    if (i == j) s += 0.001f;
    ws[WS_R + e] = s;
  }
}

__device__ __forceinline__ float sigm(float x) { return 1.0f / (1.0f + expf(-x)); }
__device__ __forceinline__ float dotv(f32x4 a, f32x4 b) {
  return a[0] * b[0] + a[1] * b[1] + a[2] * b[2] + a[3] * b[3];
}
__device__ __forceinline__ void st_nt(float* p, float v) { __builtin_nontemporal_store(v, p); }
__device__ __forceinline__ void st_nt4(float* p, f32x4 v) {
  __builtin_nontemporal_store(v, (f32x4*)p);
}

__device__ __forceinline__ float dot2f(unsigned a, unsigned b, float c) {
#if __has_builtin(__builtin_amdgcn_fdot2)
  typedef _Float16 h2 __attribute__((ext_vector_type(2)));
  union U { unsigned u; h2 h; };
  U ua, ub; ua.u = a; ub.u = b;
  return __builtin_amdgcn_fdot2(ua.h, ub.h, c, false);
#else
  union U { unsigned u; _Float16 h[2]; };
  U ua, ub; ua.u = a; ub.u = b;
  return c + (float)ua.h[0] * (float)ub.h[0] + (float)ua.h[1] * (float)ub.h[1];
#endif
}

// ============================ Kernel 1: LSTM chain ============================
struct alignas(16) LS {
  unsigned ap[8];
  unsigned h0p[64];
  unsigned h1p[64];
  float g[G4H];
  float lgp[16];
};

__global__ void __launch_bounds__(NTHR, 2) ssm_lstm_kernel(
    const float* __restrict__ as_, const float* __restrict__ AK, const float* __restrict__ CK,
    const float* __restrict__ Wout, const float* __restrict__ bout,
    const float* __restrict__ ws, float* __restrict__ out) {
  __shared__ LS s;
  const int tid = threadIdx.x;
  const int b = blockIdx.x;
  const unsigned* wsu = (const unsigned*)ws;
  const uint4* Wg = (const uint4*)(wsu + WS_WQ);
  const f32x4* AK4 = (const f32x4*)AK;
  const f32x4* CK4 = (const f32x4*)CK;

  float* o_As = out + (size_t)T_STEPS * B_SZ * ZD + (size_t)T_STEPS * B_SZ * ZD * ZD +
                (size_t)T_STEPS * B_SZ * ZD + (size_t)T_STEPS * B_SZ * ZD * ZD;
  float* o_Cs = o_As + (size_t)(T_STEPS + 1) * B_SZ * ZD * ZD;
  float* o_a = o_Cs + (size_t)(T_STEPS + 1) * B_SZ * AD * ZD;

  const uint4* h0p4 = (const uint4*)s.h0p;
  const uint4* h1p4 = (const uint4*)s.h1p;
  const uint4* ap4 = (const uint4*)s.ap;

  unsigned wi0r[8];
  #pragma unroll
  for (int k = 0; k < 8; ++k) wi0r[k] = wsu[WS_WI0 + k * 512 + tid];
  const float bs0r = ws[WS_BS0 + tid];
  const float bs1r = ws[WS_BS1 + tid];
  float woutr[8];
  #pragma unroll
  for (int gi = 0; gi < KM; ++gi) woutr[gi] = (tid < HID) ? Wout[gi * HID + tid] : 0.f;
  float boutr[8];
  #pragma unroll
  for (int k = 0; k < KM; ++k) boutr[k] = bout[k];

  float c0r = 0.f, c1r = 0.f;

  if (tid < 64) { s.h0p[tid] = 0u; s.h1p[tid] = 0u; }
  if (tid < AD) {
    float v = as_[(size_t)b * AD + tid];
    ((__half*)s.ap)[tid] = __float2half_rn(v);
    st_nt(&o_a[(size_t)b * AD + tid], v);
  }
  if (tid < 256) {  // o_As[0] (w0 = ones)
    f32x4 acc = {0.f, 0.f, 0.f, 0.f};
    #pragma unroll
    for (int k = 0; k < KM; ++k) acc += AK4[k * 256 + tid];
    st_nt4(&o_As[(size_t)b * 1024 + tid * 4], acc);
  } else if (tid < 384) {  // o_Cs[0]
    int idx = tid - 256;
    f32x4 acc = {0.f, 0.f, 0.f, 0.f};
    #pragma unroll
    for (int k = 0; k < KM; ++k) acc += CK4[k * 128 + idx];
    st_nt4(&o_Cs[(size_t)b * 512 + idx * 4], acc);
  }
  __syncthreads();

  for (int t = 0; t < T_STEPS; ++t) {
    const size_t tb2 = (size_t)(t + 1) * B_SZ + b;

    // A: L0 gates (stream W_hh0)
    {
      float acc = bs0r;
      #pragma unroll
      for (int k4 = 0; k4 < 2; ++k4) {
        uint4 av = ap4[k4];
        acc = dot2f(av.x, wi0r[k4 * 4 + 0], acc);
        acc = dot2f(av.y, wi0r[k4 * 4 + 1], acc);
        acc = dot2f(av.z, wi0r[k4 * 4 + 2], acc);
        acc = dot2f(av.w, wi0r[k4 * 4 + 3], acc);
      }
      #pragma unroll
      for (int d4 = 0; d4 < 16; ++d4) {
        uint4 w = Wg[d4 * 512 + tid];
        uint4 hv = h0p4[d4];
        acc = dot2f(hv.x, w.x, acc);
        acc = dot2f(hv.y, w.y, acc);
        acc = dot2f(hv.z, w.z, acc);
        acc = dot2f(hv.w, w.w, acc);
      }
      s.g[tid] = acc;
    }
    __syncthreads();

    // B: h0/c0
    if (tid < HID) {
      float ig = sigm(s.g[tid]);
      float fg = sigm(s.g[HID + tid]);
      float gg = tanhf(s.g[2 * HID + tid]);
      float og = sigm(s.g[3 * HID + tid]);
      c0r = fg * c0r + ig * gg;
      ((__half*)s.h0p)[tid] = __float2half_rn(og * tanhf(c0r));
    }
    __syncthreads();

    // C: L1 gates (stream W_ih1 + W_hh1)
    {
      float acc = bs1r;
      #pragma unroll
      for (int d4 = 0; d4 < 16; ++d4) {
        uint4 w = Wg[(16 + d4) * 512 + tid];
        uint4 hv = h0p4[d4];
        acc = dot2f(hv.x, w.x, acc);
        acc = dot2f(hv.y, w.y, acc);
        acc = dot2f(hv.z, w.z, acc);
        acc = dot2f(hv.w, w.w, acc);
      }
      #pragma unroll
      for (int d4 = 0; d4 < 16; ++d4) {
        uint4 w = Wg[(32 + d4) * 512 + tid];
        uint4 hv = h1p4[d4];
        acc = dot2f(hv.x, w.x, acc);
        acc = dot2f(hv.y, w.y, acc);
        acc = dot2f(hv.z, w.z, acc);
        acc = dot2f(hv.w, w.w, acc);
      }
      s.g[tid] = acc;
    }
    __syncthreads();

    // D: h1/c1 + logit partials
    if (tid < HID) {
      float ig = sigm(s.g[tid]);
      float fg = sigm(s.g[HID + tid]);
      float gg = tanhf(s.g[2 * HID + tid]);
      float og = sigm(s.g[3 * HID + tid]);
      c1r = fg * c1r + ig * gg;
      float h1u = og * tanhf(c1r);
      ((__half*)s.h1p)[tid] = __float2half_rn(h1u);
      int w2 = tid >> 6, lane = tid & 63;
      #pragma unroll
      for (int gi = 0; gi < KM; ++gi) {
        float p = woutr[gi] * h1u;
        #pragma unroll
        for (int m = 32; m >= 1; m >>= 1) p += __shfl_xor(p, m);
        if (lane == 0) s.lgp[w2 * KM + gi] = p;
      }
    }
    __syncthreads();

    // E: softmax + einsum outputs + a prefetch
    {
      float lg[KM];
      float mx = -1e30f;
      #pragma unroll
      for (int k = 0; k < KM; ++k) {
        lg[k] = s.lgp[k] + s.lgp[KM + k] + boutr[k];
        mx = fmaxf(mx, lg[k]);
      }
      float sum = 0.f;
      #pragma unroll
      for (int k = 0; k < KM; ++k) { lg[k] = expf(lg[k] - mx); sum += lg[k]; }
      float inv = 1.0f / sum;
      #pragma unroll
      for (int k = 0; k < KM; ++k) lg[k] *= inv;
      if (tid < 256) {
        f32x4 acc = {0.f, 0.f, 0.f, 0.f};
        #pragma unroll
        for (int k = 0; k < KM; ++k) acc += lg[k] * AK4[k * 256 + tid];
        st_nt4(&o_As[tb2 * 1024 + tid * 4], acc);
      } else if (tid < 384) {
        int idx = tid - 256;
        f32x4 acc = {0.f, 0.f, 0.f, 0.f};
        #pragma unroll
        for (int k = 0; k < KM; ++k) acc += lg[k] * CK4[k * 128 + idx];
        st_nt4(&o_Cs[tb2 * 512 + idx * 4], acc);
      } else if (tid >= 448 && tid < 448 + AD && t < T_STEPS - 1) {
        int i = tid - 448;
        float v = as_[tb2 * AD + i];
        ((__half*)s.ap)[i] = __float2half_rn(v);
        st_nt(&o_a[tb2 * AD + i], v);
      }
    }
    __syncthreads();
  }
}

// ========== Kernel 2: Kalman chain (1 wave/batch, barrier-free, prefetched) ==========
// All per-thread register arrays are indexed with COMPILE-TIME constants only
// (round 12's runtime "(x+rq)&3" stagger demoted them to scratch: VGPR 256,
// +143 MB writes, 8x regression — rule #20).
struct alignas(16) KS {
  float P[ZD * 36];      // cov_p (symmetric)
  float An[ZD * 36];     // A_next
  float Mt[ZD * 36];     // cov_t rows; reused for M2
  float MtT[ZD * 36];    // transposes
  float Sy[ZD * 36];     // sym(cov_t)
  float ACt[ZD * 36];
  float Qs[ZD * 36];
  float C[AD * 36];
  float Aug[AD * 52];    // [S(16) | CP(32)] per row
  float Kk[ZD * 20];
  float Rs[AD * AD];
  float meanp[ZD], meant[ZD], r[AD], af[AD];
};

__global__ void __launch_bounds__(64, 1) ssm_kalman_kernel(
    const float* __restrict__ as_, const float* __restrict__ initm,
    const float* __restrict__ initc, const float* __restrict__ ws,
    float* __restrict__ out) {
  __shared__ KS s;
  const int l = threadIdx.x;
  const int b = blockIdx.x;
  const int rq = l >> 3, cq = l & 7;   // 4x4 tile coords for 32x32 outputs
  const int i16 = l >> 2, q4 = l & 3;  // 16-row phases

  float* o_means = out;
  float* o_covs = o_means + (size_t)T_STEPS * B_SZ * ZD;
  float* o_nmean = o_covs + (size_t)T_STEPS * B_SZ * ZD * ZD;
  float* o_ncovs = o_nmean + (size_t)T_STEPS * B_SZ * ZD;
  const float* o_As = o_ncovs + (size_t)T_STEPS * B_SZ * ZD * ZD;
  const float* o_Cs = o_As + (size_t)(T_STEPS + 1) * B_SZ * ZD * ZD;

  f32x4* P4 = (f32x4*)s.P;        // stride 9
  f32x4* An4 = (f32x4*)s.An;
  f32x4* Mt4 = (f32x4*)s.Mt;
  f32x4* MtT4 = (f32x4*)s.MtT;
  f32x4* Sy4 = (f32x4*)s.Sy;
  f32x4* ACt4 = (f32x4*)s.ACt;
  f32x4* Q4 = (f32x4*)s.Qs;
  f32x4* C4 = (f32x4*)s.C;
  f32x4* Aug4 = (f32x4*)s.Aug;    // stride 13; right half at +4
  f32x4* Kk4 = (f32x4*)s.Kk;      // stride 5
  f32x4* af4 = (f32x4*)s.af;
  const f32x4* r4 = (const f32x4*)s.r;
  const f32x4* meanp4 = (const f32x4*)s.meanp;
  const f32x4* meant4 = (const f32x4*)s.meant;

  // ---- init ----
  #pragma unroll
  for (int q = 0; q < 16; ++q) {
    int e = q * 64 + l;
    s.P[(e >> 5) * 36 + (e & 31)] = initc[e];
    s.Qs[(e >> 5) * 36 + (e & 31)] = ws[WS_Q + e];
  }
  #pragma unroll
  for (int q = 0; q < 4; ++q) s.Rs[q * 64 + l] = ws[WS_R + q * 64 + l];
  if (l < ZD) s.meanp[l] = initm[l];
  {
    const f32x4* gc = (const f32x4*)&o_Cs[(size_t)b * 512];
    C4[(l >> 3) * 9 + (l & 7)] = gc[l];
    { int idx = 64 + l; C4[(idx >> 3) * 9 + (idx & 7)] = gc[idx]; }
    const f32x4* ga = (const f32x4*)&o_As[((size_t)B_SZ + b) * 1024];
    #pragma unroll
    for (int q = 0; q < 4; ++q) { int idx = q * 64 + l; An4[(idx >> 3) * 9 + (idx & 7)] = ga[idx]; }
    if (l < 4) af4[l] = ((const f32x4*)&as_[(size_t)b * AD])[l];
  }
  __builtin_amdgcn_wave_barrier();

  for (int t = 0; t < T_STEPS; ++t) {
    const size_t tb = (size_t)t * B_SZ + b;

    // P0: issue prefetch for step t+1 (kept in registers until P9)
    f32x4 pfC0 = {0,0,0,0}, pfC1 = {0,0,0,0};
    f32x4 pfA0 = {0,0,0,0}, pfA1 = {0,0,0,0}, pfA2 = {0,0,0,0}, pfA3 = {0,0,0,0};
    f32x4 pfa = {0,0,0,0};
    const bool pf = (t < T_STEPS - 1);
    if (pf) {
      const f32x4* gc = (const f32x4*)&o_Cs[(tb + B_SZ) * 512];
      pfC0 = gc[l];
      pfC1 = gc[64 + l];
      const f32x4* ga = (const f32x4*)&o_As[(tb + 2 * B_SZ) * 1024];
      pfA0 = ga[l];
      pfA1 = ga[64 + l];
      pfA2 = ga[128 + l];
      pfA3 = ga[192 + l];
      if (l < 4) pfa = ((const f32x4*)&as_[(tb + B_SZ) * AD])[l];
    }

    // P1: CP = C @ P (P symmetric -> row dots) -> Aug right half
    {
      const int i0 = rq * 2, i1 = i0 + 1;
      float a00 = 0.f, a01 = 0.f, a02 = 0.f, a03 = 0.f;
      float a10 = 0.f, a11 = 0.f, a12 = 0.f, a13 = 0.f;
      #pragma unroll
      for (int k4 = 0; k4 < 8; ++k4) {
        f32x4 c0 = C4[i0 * 9 + k4], c1 = C4[i1 * 9 + k4];
        f32x4 p0 = P4[(4 * cq + 0) * 9 + k4];
        f32x4 p1 = P4[(4 * cq + 1) * 9 + k4];
        f32x4 p2 = P4[(4 * cq + 2) * 9 + k4];
        f32x4 p3 = P4[(4 * cq + 3) * 9 + k4];
        a00 += dotv(c0, p0); a01 += dotv(c0, p1); a02 += dotv(c0, p2); a03 += dotv(c0, p3);
        a10 += dotv(c1, p0); a11 += dotv(c1, p1); a12 += dotv(c1, p2); a13 += dotv(c1, p3);
      }
      f32x4 v0 = {a00, a01, a02, a03};
      f32x4 v1 = {a10, a11, a12, a13};
      Aug4[i0 * 13 + 4 + cq] = v0;
      Aug4[i1 * 13 + 4 + cq] = v1;
    }
    __builtin_amdgcn_wave_barrier();

    // P2: S = CP C^T + R -> Aug left; r = a - C meanp (lanes<16)
    {
      float b0 = s.Rs[i16 * AD + 4 * q4 + 0];
      float b1 = s.Rs[i16 * AD + 4 * q4 + 1];
      float b2 = s.Rs[i16 * AD + 4 * q4 + 2];
      float b3 = s.Rs[i16 * AD + 4 * q4 + 3];
      #pragma unroll
      for (int k4 = 0; k4 < 8; ++k4) {
        f32x4 cpi = Aug4[i16 * 13 + 4 + k4];  // CP row i16, chunk k4
        b0 += dotv(cpi, C4[(4 * q4 + 0) * 9 + k4]);
        b1 += dotv(cpi, C4[(4 * q4 + 1) * 9 + k4]);
        b2 += dotv(cpi, C4[(4 * q4 + 2) * 9 + k4]);
        b3 += dotv(cpi, C4[(4 * q4 + 3) * 9 + k4]);
      }
      f32x4 v = {b0, b1, b2, b3};
      Aug4[i16 * 13 + q4] = v;
      if (l < AD) {
        float rr = s.af[l];
        #pragma unroll
        for (int k4 = 0; k4 < 8; ++k4) rr -= dotv(C4[l * 9 + k4], meanp4[k4]);
        s.r[l] = rr;
      }
    }
    __builtin_amdgcn_wave_barrier();

    // P3: GJ on [S | CP] -> K rows (register columns, shfl)
    {
      const int lc = (l < 48) ? l : 47;
      float col[16];
      #pragma unroll
      for (int i = 0; i < AD; ++i) col[i] = s.Aug[i * 52 + lc];
      #pragma unroll
      for (int j = 0; j < AD; ++j) {
        float pd = __shfl(col[j], j);
        float pinv = 1.0f / pd;
        float oldj = col[j];
        #pragma unroll
        for (int i = 0; i < AD; ++i) {
          if (i == j) continue;
          float fi = __shfl(col[i], j);
          col[i] = fmaf(-(fi * pinv), oldj, col[i]);
        }
        col[j] = oldj * pinv;
      }
      if (l >= AD && l < AD + ZD) {
        int rr = l - AD;
        f32x4 v0 = {col[0], col[1], col[2], col[3]};
        f32x4 v1 = {col[4], col[5], col[6], col[7]};
        f32x4 v2 = {col[8], col[9], col[10], col[11]};
        f32x4 v3 = {col[12], col[13], col[14], col[15]};
        Kk4[rr * 5 + 0] = v0;
        Kk4[rr * 5 + 1] = v1;
        Kk4[rr * 5 + 2] = v2;
        Kk4[rr * 5 + 3] = v3;
      }
    }
    __builtin_amdgcn_wave_barrier();

    // P4: mean_t (lanes<32) + cov_t = P - K@CP -> Mt, MtT (4x4 tile, k4-outer)
    {
      if (l < ZD) {
        float acc = s.meanp[l];
        #pragma unroll
        for (int m = 0; m < 4; ++m) acc += dotv(Kk4[l * 5 + m], r4[m]);
        s.meant[l] = acc;
        st_nt(&o_means[tb * ZD + l], acc);
      }
      f32x4 av0 = {0,0,0,0}, av1 = {0,0,0,0}, av2 = {0,0,0,0}, av3 = {0,0,0,0};
      #pragma unroll
      for (int k4 = 0; k4 < 4; ++k4) {
        f32x4 k0 = Kk4[(4 * rq + 0) * 5 + k4];
        f32x4 k1 = Kk4[(4 * rq + 1) * 5 + k4];
        f32x4 k2 = Kk4[(4 * rq + 2) * 5 + k4];
        f32x4 k3 = Kk4[(4 * rq + 3) * 5 + k4];
        #pragma unroll
        for (int kk = 0; kk < 4; ++kk) {
          f32x4 cpk = Aug4[(4 * k4 + kk) * 13 + 4 + cq];  // CP row k, cols 4cq..
          av0 += k0[kk] * cpk;
          av1 += k1[kk] * cpk;
          av2 += k2[kk] * cpk;
          av3 += k3[kk] * cpk;
        }
      }
      f32x4 m0 = P4[(4 * rq + 0) * 9 + cq] - av0;
      f32x4 m1 = P4[(4 * rq + 1) * 9 + cq] - av1;
      f32x4 m2 = P4[(4 * rq + 2) * 9 + cq] - av2;
      f32x4 m3 = P4[(4 * rq + 3) * 9 + cq] - av3;
      Mt4[(4 * rq + 0) * 9 + cq] = m0;
      Mt4[(4 * rq + 1) * 9 + cq] = m1;
      Mt4[(4 * rq + 2) * 9 + cq] = m2;
      Mt4[(4 * rq + 3) * 9 + cq] = m3;
      #pragma unroll
      for (int jj = 0; jj < 4; ++jj) {
        f32x4 tv = {m0[jj], m1[jj], m2[jj], m3[jj]};
        MtT4[(4 * cq + jj) * 9 + rq] = tv;
      }
    }
    __builtin_amdgcn_wave_barrier();

    // P5: Sy = 0.5(Mt+MtT) -> Sy + covs out
    {
      int i = l >> 1, cb = (l & 1) * 4;
      #pragma unroll
      for (int c = 0; c < 4; ++c) {
        f32x4 sv = 0.5f * (Mt4[i * 9 + cb + c] + MtT4[i * 9 + cb + c]);
        Sy4[i * 9 + cb + c] = sv;
        st_nt4(&o_covs[tb * 1024 + i * 32 + (cb + c) * 4], sv);
      }
    }
    __builtin_amdgcn_wave_barrier();

    // P6: ACt = An @ Sy (Sy symmetric -> row dots; 4x4 tile, k4-outer)
    {
      float c00=0,c01=0,c02=0,c03=0, c10=0,c11=0,c12=0,c13=0;
      float c20=0,c21=0,c22=0,c23=0, c30=0,c31=0,c32=0,c33=0;
      #pragma unroll
      for (int k4 = 0; k4 < 8; ++k4) {
        f32x4 an0 = An4[(4 * rq + 0) * 9 + k4];
        f32x4 an1 = An4[(4 * rq + 1) * 9 + k4];
        f32x4 an2 = An4[(4 * rq + 2) * 9 + k4];
        f32x4 an3 = An4[(4 * rq + 3) * 9 + k4];
        f32x4 sy0 = Sy4[(4 * cq + 0) * 9 + k4];
        f32x4 sy1 = Sy4[(4 * cq + 1) * 9 + k4];
        f32x4 sy2 = Sy4[(4 * cq + 2) * 9 + k4];
        f32x4 sy3 = Sy4[(4 * cq + 3) * 9 + k4];
        c00 += dotv(an0, sy0); c01 += dotv(an0, sy1); c02 += dotv(an0, sy2); c03 += dotv(an0, sy3);
        c10 += dotv(an1, sy0); c11 += dotv(an1, sy1); c12 += dotv(an1, sy2); c13 += dotv(an1, sy3);
        c20 += dotv(an2, sy0); c21 += dotv(an2, sy1); c22 += dotv(an2, sy2); c23 += dotv(an2, sy3);
        c30 += dotv(an3, sy0); c31 += dotv(an3, sy1); c32 += dotv(an3, sy2); c33 += dotv(an3, sy3);
      }
      f32x4 v0 = {c00, c01, c02, c03};
      f32x4 v1 = {c10, c11, c12, c13};
      f32x4 v2 = {c20, c21, c22, c23};
      f32x4 v3 = {c30, c31, c32, c33};
      ACt4[(4 * rq + 0) * 9 + cq] = v0;
      ACt4[(4 * rq + 1) * 9 + cq] = v1;
      ACt4[(4 * rq + 2) * 9 + cq] = v2;
      ACt4[(4 * rq + 3) * 9 + cq] = v3;
    }
    __builtin_amdgcn_wave_barrier();

    // P7: M2 = ACt @ An^T -> Mt/MtT (reuse) + meanp' = An @ mean_t (lanes<32)
    {
      if (l < ZD) {
        float acc = 0.f;
        #pragma unroll
        for (int k4 = 0; k4 < 8; ++k4) acc += dotv(An4[l * 9 + k4], meant4[k4]);
        s.meanp[l] = acc;
        st_nt(&o_nmean[tb * ZD + l], acc);
      }
      float c00=0,c01=0,c02=0,c03=0, c10=0,c11=0,c12=0,c13=0;
      float c20=0,c21=0,c22=0,c23=0, c30=0,c31=0,c32=0,c33=0;
      #pragma unroll
      for (int k4 = 0; k4 < 8; ++k4) {
        f32x4 ac0 = ACt4[(4 * rq + 0) * 9 + k4];
        f32x4 ac1 = ACt4[(4 * rq + 1) * 9 + k4];
        f32x4 ac2 = ACt4[(4 * rq + 2) * 9 + k4];
        f32x4 ac3 = ACt4[(4 * rq + 3) * 9 + k4];
        f32x4 an0 = An4[(4 * cq + 0) * 9 + k4];
        f32x4 an1 = An4[(4 * cq + 1) * 9 + k4];
        f32x4 an2 = An4[(4 * cq + 2) * 9 + k4];
        f32x4 an3 = An4[(4 * cq + 3) * 9 + k4];
        c00 += dotv(ac0, an0); c01 += dotv(ac0, an1); c02 += dotv(ac0, an2); c03 += dotv(ac0, an3);
        c10 += dotv(ac1, an0); c11 += dotv(ac1, an1); c12 += dotv(ac1, an2); c13 += dotv(ac1, an3);
        c20 += dotv(ac2, an0); c21 += dotv(ac2, an1); c22 += dotv(ac2, an2); c23 += dotv(ac2, an3);
        c30 += dotv(ac3, an0); c31 += dotv(ac3, an1); c32 += dotv(ac3, an2); c33 += dotv(ac3, an3);
      }
      f32x4 m0 = {c00, c01, c02, c03};
      f32x4 m1 = {c10, c11, c12, c13};
      f32x4 m2 = {c20, c21, c22, c23};
      f32x4 m3 = {c30, c31, c32, c33};
      Mt4[(4 * rq + 0) * 9 + cq] = m0;
      Mt4[(4 * rq + 1) * 9 + cq] = m1;
      Mt4[(4 * rq + 2) * 9 + cq] = m2;
      Mt4[(4 * rq + 3) * 9 + cq] = m3;
      #pragma unroll
      for (int jj = 0; jj < 4; ++jj) {
        f32x4 tv = {m0[jj], m1[jj], m2[jj], m3[jj]};
        MtT4[(4 * cq + jj) * 9 + rq] = tv;
      }
    }
    __builtin_amdgcn_wave_barrier();

    // P8: P' = 0.5(M2+M2^T) + Q -> P + ncovs out
    {
      int i = l >> 1, cb = (l & 1) * 4;
      #pragma unroll
      for (int c = 0; c < 4; ++c) {
        f32x4 pv = 0.5f * (Mt4[i * 9 + cb + c] + MtT4[i * 9 + cb + c]) + Q4[i * 9 + cb + c];
        P4[i * 9 + cb + c] = pv;
        st_nt4(&o_ncovs[tb * 1024 + i * 32 + (cb + c) * 4], pv);
      }
    }
    __builtin_amdgcn_wave_barrier();

    // P9: commit prefetch to LDS for step t+1
    if (pf) {
      C4[(l >> 3) * 9 + (l & 7)] = pfC0;
      { int idx = 64 + l; C4[(idx >> 3) * 9 + (idx & 7)] = pfC1; }
      An4[(l >> 3) * 9 + (l & 7)] = pfA0;
      { int idx = 64 + l;  An4[(idx >> 3) * 9 + (idx & 7)] = pfA1; }
      { int idx = 128 + l; An4[(idx >> 3) * 9 + (idx & 7)] = pfA2; }
      { int idx = 192 + l; An4[(idx >> 3) * 9 + (idx & 7)] = pfA3; }
      if (l < 4) af4[l] = pfa;
    }
    __builtin_amdgcn_wave_barrier();
  }
}

extern "C" void kernel_launch(void* const* d_in, const int* in_sizes, int n_in,
                              void* d_out, int out_size, void* d_ws, size_t ws_size,
                              hipStream_t stream) {
  const float* as_ = (const float*)d_in[0];
  const float* AK = (const float*)d_in[1];
  const float* CK = (const float*)d_in[2];
  const float* QL = (const float*)d_in[3];
  const float* RL = (const float*)d_in[4];
  const float* initm = (const float*)d_in[5];
  const float* initc = (const float*)d_in[6];
  const float* Wih0 = (const float*)d_in[7];
  const float* Whh0 = (const float*)d_in[8];
  const float* bih0 = (const float*)d_in[9];
  const float* bhh0 = (const float*)d_in[10];
  const float* Wih1 = (const float*)d_in[11];
  const float* Whh1 = (const float*)d_in[12];
  const float* bih1 = (const float*)d_in[13];
  const float* bhh1 = (const float*)d_in[14];
  const float* Wout = (const float*)d_in[15];
  const float* bout = (const float*)d_in[16];
  float* ws = (float*)d_ws;
  float* out = (float*)d_out;

  ssm_prep_kernel<<<16, 256, 0, stream>>>(Wih0, Whh0, Wih1, Whh1, bih0, bhh0, bih1, bhh1,
                                          QL, RL, ws);
  ssm_lstm_kernel<<<B_SZ, NTHR, 0, stream>>>(as_, AK, CK, Wout, bout, ws, out);
  ssm_kalman_kernel<<<B_SZ, 64, 0, stream>>>(as_, initm, initc, ws, out);
}

// Round 14
// 1587.634 us; speedup vs baseline: 8.2782x; 1.1933x over previous
//
#include <hip/hip_runtime.h>
#include <hip/hip_fp16.h>
#include <math.h>

#define T_STEPS 128
#define B_SZ 256
#define AD 16
#define ZD 32
#define KM 8
#define HID 128
#define G4H 512
#define NTHR 512

// ws layout (4-byte word offsets)
#define WS_WQ   0
#define WS_WI0  98304
#define WS_BS0  102400
#define WS_BS1  102912
#define WS_Q    103424
#define WS_R    104448

typedef float f32x4 __attribute__((ext_vector_type(4)));

__device__ __forceinline__ unsigned pk16(float lo, float hi) {
  unsigned a = __half_as_ushort(__float2half_rn(lo));
  unsigned b = __half_as_ushort(__float2half_rn(hi));
  return a | (b << 16);
}

__global__ void ssm_prep_kernel(const float* __restrict__ Wih0, const float* __restrict__ Whh0,
                                const float* __restrict__ Wih1, const float* __restrict__ Whh1,
                                const float* __restrict__ bih0, const float* __restrict__ bhh0,
                                const float* __restrict__ bih1, const float* __restrict__ bhh1,
                                const float* __restrict__ QL, const float* __restrict__ RL,
                                float* __restrict__ ws) {
  unsigned* wsu = (unsigned*)ws;
  int tid = blockIdx.x * blockDim.x + threadIdx.x;
  int nt = gridDim.x * blockDim.x;
  for (int j = tid; j < G4H; j += nt) {
    for (int d4 = 0; d4 < 48; ++d4) {
      for (int m = 0; m < 4; ++m) {
        int dd = (d4 & 15) * 4 + m;
        const float* src = (d4 < 16) ? Whh0 : (d4 < 32) ? Wih1 : Whh1;
        wsu[WS_WQ + (d4 * 512 + j) * 4 + m] =
            pk16(src[j * 128 + 2 * dd], src[j * 128 + 2 * dd + 1]);
      }
    }
    for (int k = 0; k < 8; ++k)
      wsu[WS_WI0 + k * 512 + j] = pk16(Wih0[j * 16 + 2 * k], Wih0[j * 16 + 2 * k + 1]);
    ws[WS_BS0 + j] = bih0[j] + bhh0[j];
    ws[WS_BS1 + j] = bih1[j] + bhh1[j];
  }
  for (int e = tid; e < ZD * ZD; e += nt) {
    int i = e >> 5, j = e & 31;
    float s = 0.f;
    for (int k = 0; k < ZD; ++k) s += QL[i * ZD + k] * QL[j * ZD + k];
    if (i == j) s += 0.001f;
    ws[WS_Q + e] = s;
  }
  for (int e = tid; e < AD * AD; e += nt) {
    int i = e >> 4, j = e & 15;
    float s = 0.f;
    for (int k = 0; k < AD; ++k) s += RL[i * AD + k] * RL[j * AD + k];
    if (i == j) s += 0.001f;
    ws[WS_R + e] = s;
  }
}

__device__ __forceinline__ float sigm(float x) { return 1.0f / (1.0f + expf(-x)); }
__device__ __forceinline__ float dotv(f32x4 a, f32x4 b) {
  return a[0] * b[0] + a[1] * b[1] + a[2] * b[2] + a[3] * b[3];
}
__device__ __forceinline__ void st_nt(float* p, float v) { __builtin_nontemporal_store(v, p); }
__device__ __forceinline__ void st_nt4(float* p, f32x4 v) {
  __builtin_nontemporal_store(v, (f32x4*)p);
}

__device__ __forceinline__ float dot2f(unsigned a, unsigned b, float c) {
#if __has_builtin(__builtin_amdgcn_fdot2)
  typedef _Float16 h2 __attribute__((ext_vector_type(2)));
  union U { unsigned u; h2 h; };
  U ua, ub; ua.u = a; ub.u = b;
  return __builtin_amdgcn_fdot2(ua.h, ub.h, c, false);
#else
  union U { unsigned u; _Float16 h[2]; };
  U ua, ub; ua.u = a; ub.u = b;
  return c + (float)ua.h[0] * (float)ub.h[0] + (float)ua.h[1] * (float)ub.h[1];
#endif
}

// ============================ Kernel 1: LSTM chain ============================
struct alignas(16) LS {
  unsigned ap[8];
  unsigned h0p[64];
  unsigned h1p[64];
  float g[G4H];
  float lgp[16];
};

__global__ void __launch_bounds__(NTHR, 2) ssm_lstm_kernel(
    const float* __restrict__ as_, const float* __restrict__ AK, const float* __restrict__ CK,
    const float* __restrict__ Wout, const float* __restrict__ bout,
    const float* __restrict__ ws, float* __restrict__ out) {
  __shared__ LS s;
  const int tid = threadIdx.x;
  const int b = blockIdx.x;
  const unsigned* wsu = (const unsigned*)ws;
  const uint4* Wg = (const uint4*)(wsu + WS_WQ);
  const f32x4* AK4 = (const f32x4*)AK;
  const f32x4* CK4 = (const f32x4*)CK;

  float* o_As = out + (size_t)T_STEPS * B_SZ * ZD + (size_t)T_STEPS * B_SZ * ZD * ZD +
                (size_t)T_STEPS * B_SZ * ZD + (size_t)T_STEPS * B_SZ * ZD * ZD;
  float* o_Cs = o_As + (size_t)(T_STEPS + 1) * B_SZ * ZD * ZD;
  float* o_a = o_Cs + (size_t)(T_STEPS + 1) * B_SZ * AD * ZD;

  const uint4* h0p4 = (const uint4*)s.h0p;
  const uint4* h1p4 = (const uint4*)s.h1p;
  const uint4* ap4 = (const uint4*)s.ap;

  unsigned wi0r[8];
  #pragma unroll
  for (int k = 0; k < 8; ++k) wi0r[k] = wsu[WS_WI0 + k * 512 + tid];
  const float bs0r = ws[WS_BS0 + tid];
  const float bs1r = ws[WS_BS1 + tid];
  float woutr[8];
  #pragma unroll
  for (int gi = 0; gi < KM; ++gi) woutr[gi] = (tid < HID) ? Wout[gi * HID + tid] : 0.f;
  float boutr[8];
  #pragma unroll
  for (int k = 0; k < KM; ++k) boutr[k] = bout[k];

  float c0r = 0.f, c1r = 0.f;

  if (tid < 64) { s.h0p[tid] = 0u; s.h1p[tid] = 0u; }
  if (tid < AD) {
    float v = as_[(size_t)b * AD + tid];
    ((__half*)s.ap)[tid] = __float2half_rn(v);
    st_nt(&o_a[(size_t)b * AD + tid], v);
  }
  if (tid < 256) {
    f32x4 acc = {0.f, 0.f, 0.f, 0.f};
    #pragma unroll
    for (int k = 0; k < KM; ++k) acc += AK4[k * 256 + tid];
    st_nt4(&o_As[(size_t)b * 1024 + tid * 4], acc);
  } else if (tid < 384) {
    int idx = tid - 256;
    f32x4 acc = {0.f, 0.f, 0.f, 0.f};
    #pragma unroll
    for (int k = 0; k < KM; ++k) acc += CK4[k * 128 + idx];
    st_nt4(&o_Cs[(size_t)b * 512 + idx * 4], acc);
  }
  __syncthreads();

  for (int t = 0; t < T_STEPS; ++t) {
    const size_t tb2 = (size_t)(t + 1) * B_SZ + b;

    // A: L0 gates (stream W_hh0)
    {
      float acc = bs0r;
      #pragma unroll
      for (int k4 = 0; k4 < 2; ++k4) {
        uint4 av = ap4[k4];
        acc = dot2f(av.x, wi0r[k4 * 4 + 0], acc);
        acc = dot2f(av.y, wi0r[k4 * 4 + 1], acc);
        acc = dot2f(av.z, wi0r[k4 * 4 + 2], acc);
        acc = dot2f(av.w, wi0r[k4 * 4 + 3], acc);
      }
      #pragma unroll
      for (int d4 = 0; d4 < 16; ++d4) {
        uint4 w = Wg[d4 * 512 + tid];
        uint4 hv = h0p4[d4];
        acc = dot2f(hv.x, w.x, acc);
        acc = dot2f(hv.y, w.y, acc);
        acc = dot2f(hv.z, w.z, acc);
        acc = dot2f(hv.w, w.w, acc);
      }
      s.g[tid] = acc;
    }
    __syncthreads();

    // B: h0/c0
    if (tid < HID) {
      float ig = sigm(s.g[tid]);
      float fg = sigm(s.g[HID + tid]);
      float gg = tanhf(s.g[2 * HID + tid]);
      float og = sigm(s.g[3 * HID + tid]);
      c0r = fg * c0r + ig * gg;
      ((__half*)s.h0p)[tid] = __float2half_rn(og * tanhf(c0r));
    }
    __syncthreads();

    // C: L1 gates (stream W_ih1 + W_hh1)
    {
      float acc = bs1r;
      #pragma unroll
      for (int d4 = 0; d4 < 16; ++d4) {
        uint4 w = Wg[(16 + d4) * 512 + tid];
        uint4 hv = h0p4[d4];
        acc = dot2f(hv.x, w.x, acc);
        acc = dot2f(hv.y, w.y, acc);
        acc = dot2f(hv.z, w.z, acc);
        acc = dot2f(hv.w, w.w, acc);
      }
      #pragma unroll
      for (int d4 = 0; d4 < 16; ++d4) {
        uint4 w = Wg[(32 + d4) * 512 + tid];
        uint4 hv = h1p4[d4];
        acc = dot2f(hv.x, w.x, acc);
        acc = dot2f(hv.y, w.y, acc);
        acc = dot2f(hv.z, w.z, acc);
        acc = dot2f(hv.w, w.w, acc);
      }
      s.g[tid] = acc;
    }
    __syncthreads();

    // D: h1/c1 + logit partials
    if (tid < HID) {
      float ig = sigm(s.g[tid]);
      float fg = sigm(s.g[HID + tid]);
      float gg = tanhf(s.g[2 * HID + tid]);
      float og = sigm(s.g[3 * HID + tid]);
      c1r = fg * c1r + ig * gg;
      float h1u = og * tanhf(c1r);
      ((__half*)s.h1p)[tid] = __float2half_rn(h1u);
      int w2 = tid >> 6, lane = tid & 63;
      #pragma unroll
      for (int gi = 0; gi < KM; ++gi) {
        float p = woutr[gi] * h1u;
        #pragma unroll
        for (int m = 32; m >= 1; m >>= 1) p += __shfl_xor(p, m);
        if (lane == 0) s.lgp[w2 * KM + gi] = p;
      }
    }
    __syncthreads();

    // E: softmax + einsum outputs + a prefetch
    {
      float lg[KM];
      float mx = -1e30f;
      #pragma unroll
      for (int k = 0; k < KM; ++k) {
        lg[k] = s.lgp[k] + s.lgp[KM + k] + boutr[k];
        mx = fmaxf(mx, lg[k]);
      }
      float sum = 0.f;
      #pragma unroll
      for (int k = 0; k < KM; ++k) { lg[k] = expf(lg[k] - mx); sum += lg[k]; }
      float inv = 1.0f / sum;
      #pragma unroll
      for (int k = 0; k < KM; ++k) lg[k] *= inv;
      if (tid < 256) {
        f32x4 acc = {0.f, 0.f, 0.f, 0.f};
        #pragma unroll
        for (int k = 0; k < KM; ++k) acc += lg[k] * AK4[k * 256 + tid];
        st_nt4(&o_As[tb2 * 1024 + tid * 4], acc);
      } else if (tid < 384) {
        int idx = tid - 256;
        f32x4 acc = {0.f, 0.f, 0.f, 0.f};
        #pragma unroll
        for (int k = 0; k < KM; ++k) acc += lg[k] * CK4[k * 128 + idx];
        st_nt4(&o_Cs[tb2 * 512 + idx * 4], acc);
      } else if (tid >= 448 && tid < 448 + AD && t < T_STEPS - 1) {
        int i = tid - 448;
        float v = as_[tb2 * AD + i];
        ((__half*)s.ap)[i] = __float2half_rn(v);
        st_nt(&o_a[tb2 * AD + i], v);
      }
    }
    __syncthreads();
  }
}

// ===== Kernel 2: Kalman chain — 4 waves/batch (256 thr), GJ on wave 0, prefetched =====
struct alignas(16) KS {
  float P[ZD * 36];
  float An[ZD * 36];
  float Mt[ZD * 36];
  float MtT[ZD * 36];
  float Sy[ZD * 36];
  float ACt[ZD * 36];
  float Qs[ZD * 36];
  float C[AD * 36];
  float Aug[AD * 52];    // [S(16) | CP(32)] per row
  float Kk[ZD * 20];
  float Rs[AD * AD];
  float meanp[ZD], meant[ZD], r[AD], af[AD];
};

__global__ void __launch_bounds__(256, 1) ssm_kalman_kernel(
    const float* __restrict__ as_, const float* __restrict__ initm,
    const float* __restrict__ initc, const float* __restrict__ ws,
    float* __restrict__ out) {
  __shared__ KS s;
  const int l = threadIdx.x;           // 0..255
  const int b = blockIdx.x;
  const int i32 = l & 31, cq = l >> 5; // 32-row f32x4 phases (2-way-max banks)
  const int i16 = l & 15, j16 = l >> 4;// 16-row phases

  float* o_means = out;
  float* o_covs = o_means + (size_t)T_STEPS * B_SZ * ZD;
  float* o_nmean = o_covs + (size_t)T_STEPS * B_SZ * ZD * ZD;
  float* o_ncovs = o_nmean + (size_t)T_STEPS * B_SZ * ZD;
  const float* o_As = o_ncovs + (size_t)T_STEPS * B_SZ * ZD * ZD;
  const float* o_Cs = o_As + (size_t)(T_STEPS + 1) * B_SZ * ZD * ZD;

  f32x4* P4 = (f32x4*)s.P;        // stride 9
  f32x4* An4 = (f32x4*)s.An;
  f32x4* Mt4 = (f32x4*)s.Mt;
  f32x4* MtT4 = (f32x4*)s.MtT;
  f32x4* Sy4 = (f32x4*)s.Sy;
  f32x4* ACt4 = (f32x4*)s.ACt;
  f32x4* Q4 = (f32x4*)s.Qs;
  f32x4* C4 = (f32x4*)s.C;
  f32x4* Aug4 = (f32x4*)s.Aug;    // stride 13; CP at +4
  f32x4* Kk4 = (f32x4*)s.Kk;      // stride 5
  f32x4* af4 = (f32x4*)s.af;
  const f32x4* r4 = (const f32x4*)s.r;
  const f32x4* meanp4 = (const f32x4*)s.meanp;
  const f32x4* meant4 = (const f32x4*)s.meant;

  // ---- init ----
  #pragma unroll
  for (int q = 0; q < 4; ++q) {
    int e = q * 256 + l;
    s.P[(e >> 5) * 36 + (e & 31)] = initc[e];
    s.Qs[(e >> 5) * 36 + (e & 31)] = ws[WS_Q + e];
  }
  s.Rs[l] = ws[WS_R + l];
  if (l < ZD) s.meanp[l] = initm[l];
  {
    const f32x4* gc = (const f32x4*)&o_Cs[(size_t)b * 512];
    if (l < 128) C4[(l >> 3) * 9 + (l & 7)] = gc[l];
    const f32x4* ga = (const f32x4*)&o_As[((size_t)B_SZ + b) * 1024];
    An4[(l >> 3) * 9 + (l & 7)] = ga[l];
    if (l < 4) af4[l] = ((const f32x4*)&as_[(size_t)b * AD])[l];
  }
  __syncthreads();

  for (int t = 0; t < T_STEPS; ++t) {
    const size_t tb = (size_t)t * B_SZ + b;
    const bool pf = (t < T_STEPS - 1);

    // P0: issue prefetch for step t+1 (registers; C on threads >=128, An on all)
    f32x4 pfC = {0, 0, 0, 0};
    f32x4 pfA = {0, 0, 0, 0};
    f32x4 pfa = {0, 0, 0, 0};
    if (pf) {
      if (l >= 128) pfC = ((const f32x4*)&o_Cs[(tb + B_SZ) * 512])[l - 128];
      pfA = ((const f32x4*)&o_As[(tb + 2 * B_SZ) * 1024])[l];
      if (l < 4) pfa = ((const f32x4*)&as_[(tb + B_SZ) * AD])[l];
    }

    // P1: CP = C @ P (P symmetric -> row dots) -> Aug right half (2 outputs/thread)
    {
      float a0 = 0.f, a1 = 0.f;
      #pragma unroll
      for (int k4 = 0; k4 < 8; ++k4) {
        f32x4 cr = C4[i16 * 9 + k4];
        a0 += dotv(cr, P4[j16 * 9 + k4]);
        a1 += dotv(cr, P4[(j16 + 16) * 9 + k4]);
      }
      s.Aug[i16 * 52 + AD + j16] = a0;
      s.Aug[i16 * 52 + AD + j16 + 16] = a1;
    }
    __syncthreads();

    // P2: S = CP C^T + R -> Aug left (1 output/thread); r on 16 threads
    {
      float acc = s.Rs[i16 * AD + j16];
      #pragma unroll
      for (int k4 = 0; k4 < 8; ++k4)
        acc += dotv(Aug4[i16 * 13 + 4 + k4], C4[j16 * 9 + k4]);
      s.Aug[i16 * 52 + j16] = acc;
      if (l >= 240) {
        int ii = l - 240;
        float rr = s.af[ii];
        #pragma unroll
        for (int k4 = 0; k4 < 8; ++k4) rr -= dotv(C4[ii * 9 + k4], meanp4[k4]);
        s.r[ii] = rr;
      }
    }
    __syncthreads();

    // P3: wave 0 GJ -> K  |  waves 2-3 commit prefetched C (C dead after P2)
    if (l < 64) {
      const int lc = (l < 48) ? l : 47;
      float col[16];
      #pragma unroll
      for (int i = 0; i < AD; ++i) col[i] = s.Aug[i * 52 + lc];
      #pragma unroll
      for (int j = 0; j < AD; ++j) {
        float pd = __shfl(col[j], j);
        float pinv = 1.0f / pd;
        float oldj = col[j];
        #pragma unroll
        for (int i = 0; i < AD; ++i) {
          if (i == j) continue;
          float fi = __shfl(col[i], j);
          col[i] = fmaf(-(fi * pinv), oldj, col[i]);
        }
        col[j] = oldj * pinv;
      }
      if (l >= AD && l < AD + ZD) {
        int rr = l - AD;
        f32x4 v0 = {col[0], col[1], col[2], col[3]};
        f32x4 v1 = {col[4], col[5], col[6], col[7]};
        f32x4 v2 = {col[8], col[9], col[10], col[11]};
        f32x4 v3 = {col[12], col[13], col[14], col[15]};
        Kk4[rr * 5 + 0] = v0;
        Kk4[rr * 5 + 1] = v1;
        Kk4[rr * 5 + 2] = v2;
        Kk4[rr * 5 + 3] = v3;
      }
    } else if (pf && l >= 128) {
      int idx = l - 128;
      C4[(idx >> 3) * 9 + (idx & 7)] = pfC;
    }
    __syncthreads();

    // P4: cov_t = P - K@CP -> Mt, MtT (1 f32x4/thread, k4-outer)
    {
      f32x4 acc = {0.f, 0.f, 0.f, 0.f};
      #pragma unroll
      for (int k4 = 0; k4 < 4; ++k4) {
        f32x4 kv = Kk4[i32 * 5 + k4];
        #pragma unroll
        for (int kk = 0; kk < 4; ++kk) {
          f32x4 cpk = Aug4[(4 * k4 + kk) * 13 + 4 + cq];
          acc += kv[kk] * cpk;
        }
      }
      f32x4 mv = P4[i32 * 9 + cq] - acc;
      Mt4[i32 * 9 + cq] = mv;
      #pragma unroll
      for (int jj = 0; jj < 4; ++jj) s.MtT[(4 * cq + jj) * 36 + i32] = mv[jj];
    }
    __syncthreads();

    // P5: Sy = 0.5(Mt+MtT) + covs out; mean_t on lanes<32
    {
      f32x4 sv = 0.5f * (Mt4[i32 * 9 + cq] + MtT4[i32 * 9 + cq]);
      Sy4[i32 * 9 + cq] = sv;
      st_nt4(&o_covs[tb * 1024 + i32 * 32 + cq * 4], sv);
      if (l < ZD) {
        float acc = s.meanp[l];
        #pragma unroll
        for (int m = 0; m < 4; ++m) acc += dotv(Kk4[l * 5 + m], r4[m]);
        s.meant[l] = acc;
        st_nt(&o_means[tb * ZD + l], acc);
      }
    }
    __syncthreads();

    // P6: ACt = An @ Sy (Sy symmetric -> row dots; 1 f32x4/thread)
    {
      float c0 = 0.f, c1 = 0.f, c2 = 0.f, c3 = 0.f;
      #pragma unroll
      for (int k4 = 0; k4 < 8; ++k4) {
        f32x4 an = An4[i32 * 9 + k4];
        c0 += dotv(an, Sy4[(4 * cq + 0) * 9 + k4]);
        c1 += dotv(an, Sy4[(4 * cq + 1) * 9 + k4]);
        c2 += dotv(an, Sy4[(4 * cq + 2) * 9 + k4]);
        c3 += dotv(an, Sy4[(4 * cq + 3) * 9 + k4]);
      }
      f32x4 v = {c0, c1, c2, c3};
      ACt4[i32 * 9 + cq] = v;
    }
    __syncthreads();

    // P7: M2 = ACt @ An^T -> Mt/MtT; meanp' = An @ mean_t on lanes<32
    {
      if (l < ZD) {
        float acc = 0.f;
        #pragma unroll
        for (int k4 = 0; k4 < 8; ++k4) acc += dotv(An4[l * 9 + k4], meant4[k4]);
        s.meanp[l] = acc;
        st_nt(&o_nmean[tb * ZD + l], acc);
      }
      float c0 = 0.f, c1 = 0.f, c2 = 0.f, c3 = 0.f;
      #pragma unroll
      for (int k4 = 0; k4 < 8; ++k4) {
        f32x4 ac = ACt4[i32 * 9 + k4];
        c0 += dotv(ac, An4[(4 * cq + 0) * 9 + k4]);
        c1 += dotv(ac, An4[(4 * cq + 1) * 9 + k4]);
        c2 += dotv(ac, An4[(4 * cq + 2) * 9 + k4]);
        c3 += dotv(ac, An4[(4 * cq + 3) * 9 + k4]);
      }
      f32x4 mv = {c0, c1, c2, c3};
      Mt4[i32 * 9 + cq] = mv;
      #pragma unroll
      for (int jj = 0; jj < 4; ++jj) s.MtT[(4 * cq + jj) * 36 + i32] = mv[jj];
    }
    __syncthreads();

    // P8: P' = 0.5(M2+M2^T) + Q -> P + ncovs out
    {
      f32x4 pv = 0.5f * (Mt4[i32 * 9 + cq] + MtT4[i32 * 9 + cq]) + Q4[i32 * 9 + cq];
      P4[i32 * 9 + cq] = pv;
      st_nt4(&o_ncovs[tb * 1024 + i32 * 32 + cq * 4], pv);
    }
    __syncthreads();

    // P9: commit prefetched An + a
    if (pf) {
      An4[(l >> 3) * 9 + (l & 7)] = pfA;
      if (l < 4) af4[l] = pfa;
    }
    __syncthreads();
  }
}

extern "C" void kernel_launch(void* const* d_in, const int* in_sizes, int n_in,
                              void* d_out, int out_size, void* d_ws, size_t ws_size,
                              hipStream_t stream) {
  const float* as_ = (const float*)d_in[0];
  const float* AK = (const float*)d_in[1];
  const float* CK = (const float*)d_in[2];
  const float* QL = (const float*)d_in[3];
  const float* RL = (const float*)d_in[4];
  const float* initm = (const float*)d_in[5];
  const float* initc = (const float*)d_in[6];
  const float* Wih0 = (const float*)d_in[7];
  const float* Whh0 = (const float*)d_in[8];
  const float* bih0 = (const float*)d_in[9];
  const float* bhh0 = (const float*)d_in[10];
  const float* Wih1 = (const float*)d_in[11];
  const float* Whh1 = (const float*)d_in[12];
  const float* bih1 = (const float*)d_in[13];
  const float* bhh1 = (const float*)d_in[14];
  const float* Wout = (const float*)d_in[15];
  const float* bout = (const float*)d_in[16];
  float* ws = (float*)d_ws;
  float* out = (float*)d_out;

  ssm_prep_kernel<<<16, 256, 0, stream>>>(Wih0, Whh0, Wih1, Whh1, bih0, bhh0, bih1, bhh1,
                                          QL, RL, ws);
  ssm_lstm_kernel<<<B_SZ, NTHR, 0, stream>>>(as_, AK, CK, Wout, bout, ws, out);
  ssm_kalman_kernel<<<B_SZ, 256, 0, stream>>>(as_, initm, initc, ws, out);
}